// Round 2
// baseline (951.895 us; speedup 1.0000x reference)
//
#include <hip/hip_runtime.h>
#include <stdint.h>
#include <math.h>

// PatchCore 1-NN distance: pool -> bf16 emb/coreset -> MFMA GEMM with fused min -> sqrt
// B=8, C=1024, H=W=32, N=8192, M=32768

#define N_TOT 8192
#define M_TOT 32768
#define C_TOT 1024
#define EPS_ 1e-12f

// Guide-verified fragment types for mfma_f32_16x16x32_bf16 (bf16 bits in shorts)
typedef short bf16x8 __attribute__((ext_vector_type(8)));
typedef float f32x4 __attribute__((ext_vector_type(4)));

__device__ __forceinline__ unsigned short f2bf_rne(float f) {
    unsigned u = __float_as_uint(f);
    u += 0x7fffu + ((u >> 16) & 1u);
    return (unsigned short)(u >> 16);
}
__device__ __forceinline__ float bf2f(unsigned short h) {
    return __uint_as_float(((unsigned)h) << 16);
}

// ---------------- init: d2min = +inf bits, x2 = 0 ----------------
__global__ void init_kernel(unsigned* __restrict__ d2u, float* __restrict__ x2) {
    int i = blockIdx.x * blockDim.x + threadIdx.x;
    if (i < N_TOT) { d2u[i] = 0x7F800000u; x2[i] = 0.0f; }
}

// ---------------- pool 3x3 (count_include_pad) + transpose to [N,C] bf16 + partial x2 ----------------
// grid: b(8) x cchunk(32) x h(32) = 8192 blocks, 256 threads
__global__ __launch_bounds__(256) void pool_kernel(const float* __restrict__ feat,
                                                   unsigned short* __restrict__ emb,
                                                   float* __restrict__ x2) {
    int bid = blockIdx.x;
    int h  = bid & 31;
    int cc = (bid >> 5) & 31;
    int b  = bid >> 10;
    int tid = threadIdx.x;
    __shared__ float lds[32 * 97]; // 32 channels x (3 rows * 32 w), pad 97

    const float* base = feat + ((size_t)(b * 1024 + cc * 32)) * 1024; // 32 channel planes
    int g0 = (h - 1) * 32;
    #pragma unroll
    for (int it = 0; it < 12; ++it) {
        int e = tid + it * 256;      // 0..3071
        int ci = e / 96;
        int j  = e - ci * 96;        // 0..95 -> 3 contiguous rows
        int g  = g0 + j;
        float v = 0.0f;
        if (g >= 0 && g < 1024) v = base[(size_t)ci * 1024 + g];
        lds[ci * 97 + j] = v;
    }
    __syncthreads();

    int c  = tid & 31;
    int wb = tid >> 5; // 0..7
    const float inv9 = 1.0f / 9.0f;
    #pragma unroll
    for (int i = 0; i < 4; ++i) {
        int w = wb + i * 8;
        float s = 0.0f;
        #pragma unroll
        for (int rr = 0; rr < 3; ++rr) {
            int rb = c * 97 + rr * 32 + w;
            s += lds[rb];
            if (w > 0)  s += lds[rb - 1];
            if (w < 31) s += lds[rb + 1];
        }
        float p = s * inv9;
        unsigned short bh = f2bf_rne(p);
        int n = b * 1024 + h * 32 + w;
        emb[(size_t)n * 1024 + cc * 32 + c] = bh;
        float pf = bf2f(bh);
        float sq = pf * pf;
        #pragma unroll
        for (int off = 1; off < 32; off <<= 1) sq += __shfl_xor(sq, off);
        if (c == 0) atomicAdd(&x2[n], sq);
    }
}

// ---------------- coreset -> bf16 + y2 row norms ----------------
// grid: 32768 blocks (one row each), 256 threads
__global__ __launch_bounds__(256) void cs_kernel(const float* __restrict__ cs,
                                                 unsigned short* __restrict__ csb,
                                                 float* __restrict__ y2) {
    int row = blockIdx.x;
    int tid = threadIdx.x;
    float4 v = reinterpret_cast<const float4*>(cs + (size_t)row * 1024)[tid];
    ushort4 o;
    o.x = f2bf_rne(v.x); o.y = f2bf_rne(v.y);
    o.z = f2bf_rne(v.z); o.w = f2bf_rne(v.w);
    reinterpret_cast<ushort4*>(csb + (size_t)row * 1024)[tid] = o;
    float a = bf2f(o.x), b = bf2f(o.y), c = bf2f(o.z), d = bf2f(o.w);
    float s = a * a + b * b + c * c + d * d;
    #pragma unroll
    for (int off = 1; off < 64; off <<= 1) s += __shfl_xor(s, off);
    __shared__ float red[4];
    if ((tid & 63) == 0) red[tid >> 6] = s;
    __syncthreads();
    if (tid == 0) y2[row] = red[0] + red[1] + red[2] + red[3];
}

// ---------------- GEMM-min: 128x128 tile, BK=32, 4 waves, 16x16x32 bf16 MFMA ----------------
// grid: 64 n-tiles * 256 m-tiles = 16384 blocks, 256 threads
// Ordering: XCD x owns coreset slab im in [x*32, x*32+32); within the XCD,
// 8x8 supertiles (8 emb-tiles x 8 cs-tiles = 4MB) keep the working set in L2.
__global__ __launch_bounds__(256) void gemm_min_kernel(const unsigned short* __restrict__ emb,
                                                       const unsigned short* __restrict__ csb,
                                                       const float* __restrict__ x2,
                                                       const float* __restrict__ y2,
                                                       unsigned* __restrict__ d2u) {
    int bid = blockIdx.x;
    int xcd   = bid & 7;
    int local = bid >> 3;        // 0..2047
    int st    = local >> 6;      // 0..31 supertile within XCD
    int idx   = local & 63;      // 0..63 within supertile
    int si = idx >> 3;           // 0..7 emb-sub
    int sj = idx & 7;            // 0..7 cs-sub
    int in = (st & 7) * 8 + si;            // 0..63 emb tile
    int im = xcd * 32 + (st >> 3) * 8 + sj; // 0..255 coreset tile
    int nb = in * 128;
    int mb = im * 128;

    int tid  = threadIdx.x;
    int lane = tid & 63;
    int wid  = tid >> 6;
    int wr = wid >> 1, wc = wid & 1;

    __shared__ unsigned short lds[8192]; // A tile [128][32] then B tile [128][32]
    unsigned short* lA = lds;
    unsigned short* lB = lds + 4096;

    f32x4 acc[4][4];
    #pragma unroll
    for (int m = 0; m < 4; ++m)
        #pragma unroll
        for (int n = 0; n < 4; ++n) acc[m][n] = (f32x4){0.f, 0.f, 0.f, 0.f};

    const unsigned short* gA = emb + (size_t)nb * 1024;
    const unsigned short* gB = csb + (size_t)mb * 1024;

    int fr = lane & 15;        // fragment row/col index
    int kq = lane >> 4;        // k-chunk (x8)

    for (int kt = 0; kt < 32; ++kt) {
        int k0 = kt * 32;
        __syncthreads(); // previous iter's ds_reads done before overwrite
        #pragma unroll
        for (int i = 0; i < 2; ++i) {
            int seg = i * 256 + wid * 64 + lane;  // 0..511 16B segments
            int row = seg >> 2;
            int ks  = seg & 3;
            __builtin_amdgcn_global_load_lds(
                (__attribute__((address_space(1))) void*)(gA + (size_t)row * 1024 + k0 + ks * 8),
                (__attribute__((address_space(3))) void*)(lA + (i * 256 + wid * 64) * 8),
                16, 0, 0);
            __builtin_amdgcn_global_load_lds(
                (__attribute__((address_space(1))) void*)(gB + (size_t)row * 1024 + k0 + ks * 8),
                (__attribute__((address_space(3))) void*)(lB + (i * 256 + wid * 64) * 8),
                16, 0, 0);
        }
        __syncthreads(); // compiler drains vmcnt(0) before barrier

        bf16x8 af[4], bfv[4];
        #pragma unroll
        for (int m = 0; m < 4; ++m)
            af[m] = *reinterpret_cast<const bf16x8*>(&lA[(wr * 64 + m * 16 + fr) * 32 + kq * 8]);
        #pragma unroll
        for (int n = 0; n < 4; ++n)
            bfv[n] = *reinterpret_cast<const bf16x8*>(&lB[(wc * 64 + n * 16 + fr) * 32 + kq * 8]);
        #pragma unroll
        for (int m = 0; m < 4; ++m)
            #pragma unroll
            for (int n = 0; n < 4; ++n)
                acc[m][n] = __builtin_amdgcn_mfma_f32_16x16x32_bf16(af[m], bfv[n], acc[m][n], 0, 0, 0);
    }

    // epilogue: d2 = x2[row] + y2[col] - 2*dot ; min over this block's 128 cols
    // C/D layout: col = lane&15, row = (lane>>4)*4 + reg  [m89]
    int cc = lane & 15;
    int rq = (lane >> 4) * 4;
    float y2v[4];
    #pragma unroll
    for (int n = 0; n < 4; ++n) y2v[n] = y2[mb + wc * 64 + n * 16 + cc];

    #pragma unroll
    for (int m = 0; m < 4; ++m) {
        #pragma unroll
        for (int j = 0; j < 4; ++j) {
            float v = y2v[0] - 2.0f * acc[m][0][j];
            #pragma unroll
            for (int n = 1; n < 4; ++n) v = fminf(v, y2v[n] - 2.0f * acc[m][n][j]);
            int grow = nb + wr * 64 + m * 16 + rq + j;
            float d2 = x2[grow] + v;
            d2 = fmaxf(d2, EPS_);
            // min across 16 lanes (same row, 16 different cols)
            #pragma unroll
            for (int off = 1; off < 16; off <<= 1) d2 = fminf(d2, __shfl_xor(d2, off));
            if (cc == 0) atomicMin(&d2u[grow], __float_as_uint(d2)); // positive floats: uint order == float order
        }
    }
}

// ---------------- finalize: sqrt ----------------
__global__ void sqrt_kernel(const unsigned* __restrict__ d2u, float* __restrict__ out) {
    int i = blockIdx.x * blockDim.x + threadIdx.x;
    if (i < N_TOT) out[i] = sqrtf(__uint_as_float(d2u[i]));
}

extern "C" void kernel_launch(void* const* d_in, const int* in_sizes, int n_in,
                              void* d_out, int out_size, void* d_ws, size_t ws_size,
                              hipStream_t stream) {
    const float* feat = (const float*)d_in[0];   // [8,1024,32,32] fp32
    const float* cs   = (const float*)d_in[1];   // [32768,1024] fp32
    float* out = (float*)d_out;                  // [8192] fp32

    char* ws = (char*)d_ws;
    // ws layout (~84.1 MB total)
    unsigned short* emb = (unsigned short*)ws;                          // 16,777,216 B
    unsigned short* csb = (unsigned short*)(ws + 16777216);             // 67,108,864 B
    float* x2 = (float*)(ws + 16777216 + 67108864);                     // 32,768 B
    float* y2 = x2 + N_TOT;                                             // 131,072 B
    unsigned* d2u = (unsigned*)(y2 + M_TOT);                            // 32,768 B

    init_kernel<<<N_TOT / 256, 256, 0, stream>>>(d2u, x2);
    pool_kernel<<<8192, 256, 0, stream>>>(feat, emb, x2);
    cs_kernel<<<M_TOT, 256, 0, stream>>>(cs, csb, y2);
    gemm_min_kernel<<<16384, 256, 0, stream>>>(emb, csb, x2, y2, d2u);
    sqrt_kernel<<<N_TOT / 256, 256, 0, stream>>>(d2u, out);
}

// Round 4
// 885.554 us; speedup vs baseline: 1.0749x; 1.0749x over previous
//
#include <hip/hip_runtime.h>
#include <stdint.h>
#include <math.h>

// PatchCore 1-NN: pool -> bf16 emb/coreset -> 256x256-tile MFMA GEMM-min
// with 3-buffer counted-vmcnt pipeline + XOR bank swizzle -> sqrt.
// B=8, C=1024, H=W=32, N=8192, M=32768, K=1024

#define N_TOT 8192
#define M_TOT 32768
#define EPS_ 1e-12f
#define S_KT 32          // K tiles of BK=32

typedef short bf16x8 __attribute__((ext_vector_type(8)));
typedef float f32x4 __attribute__((ext_vector_type(4)));

__device__ __forceinline__ unsigned short f2bf_rne(float f) {
    unsigned u = __float_as_uint(f);
    u += 0x7fffu + ((u >> 16) & 1u);
    return (unsigned short)(u >> 16);
}
__device__ __forceinline__ float bf2f(unsigned short h) {
    return __uint_as_float(((unsigned)h) << 16);
}

// ---------------- init ----------------
__global__ void init_kernel(unsigned* __restrict__ d2u, float* __restrict__ x2) {
    int i = blockIdx.x * blockDim.x + threadIdx.x;
    if (i < N_TOT) { d2u[i] = 0x7F800000u; x2[i] = 0.0f; }
}

// ---------------- pool 3x3 + transpose to [N,C] bf16 + partial x2 ----------------
__global__ __launch_bounds__(256) void pool_kernel(const float* __restrict__ feat,
                                                   unsigned short* __restrict__ emb,
                                                   float* __restrict__ x2) {
    int bid = blockIdx.x;
    int h  = bid & 31;
    int cc = (bid >> 5) & 31;
    int b  = bid >> 10;
    int tid = threadIdx.x;
    __shared__ float lds[32 * 97];

    const float* base = feat + ((size_t)(b * 1024 + cc * 32)) * 1024;
    int g0 = (h - 1) * 32;
    #pragma unroll
    for (int it = 0; it < 12; ++it) {
        int e = tid + it * 256;
        int ci = e / 96;
        int j  = e - ci * 96;
        int g  = g0 + j;
        float v = 0.0f;
        if (g >= 0 && g < 1024) v = base[(size_t)ci * 1024 + g];
        lds[ci * 97 + j] = v;
    }
    __syncthreads();

    int c  = tid & 31;
    int wb = tid >> 5;
    const float inv9 = 1.0f / 9.0f;
    #pragma unroll
    for (int i = 0; i < 4; ++i) {
        int w = wb + i * 8;
        float s = 0.0f;
        #pragma unroll
        for (int rr = 0; rr < 3; ++rr) {
            int rb = c * 97 + rr * 32 + w;
            s += lds[rb];
            if (w > 0)  s += lds[rb - 1];
            if (w < 31) s += lds[rb + 1];
        }
        float p = s * inv9;
        unsigned short bh = f2bf_rne(p);
        int n = b * 1024 + h * 32 + w;
        emb[(size_t)n * 1024 + cc * 32 + c] = bh;
        float pf = bf2f(bh);
        float sq = pf * pf;
        #pragma unroll
        for (int off = 1; off < 32; off <<= 1) sq += __shfl_xor(sq, off);
        if (c == 0) atomicAdd(&x2[n], sq);
    }
}

// ---------------- coreset -> bf16 + y2 ----------------
__global__ __launch_bounds__(256) void cs_kernel(const float* __restrict__ cs,
                                                 unsigned short* __restrict__ csb,
                                                 float* __restrict__ y2) {
    int row = blockIdx.x;
    int tid = threadIdx.x;
    float4 v = reinterpret_cast<const float4*>(cs + (size_t)row * 1024)[tid];
    ushort4 o;
    o.x = f2bf_rne(v.x); o.y = f2bf_rne(v.y);
    o.z = f2bf_rne(v.z); o.w = f2bf_rne(v.w);
    reinterpret_cast<ushort4*>(csb + (size_t)row * 1024)[tid] = o;
    float a = bf2f(o.x), b = bf2f(o.y), c = bf2f(o.z), d = bf2f(o.w);
    float s = a * a + b * b + c * c + d * d;
    #pragma unroll
    for (int off = 1; off < 64; off <<= 1) s += __shfl_xor(s, off);
    __shared__ float red[4];
    if ((tid & 63) == 0) red[tid >> 6] = s;
    __syncthreads();
    if (tid == 0) y2[row] = red[0] + red[1] + red[2] + red[3];
}

// ---------------- GEMM-min: 256x256 tile, BK=32, 8 waves, 3-buffer pipeline ----------------
// grid: 32 emb-tiles x 128 cs-tiles = 4096 blocks, 512 threads.
// LDS buffer b: A [256 rows][4 slots of 16B, XOR-swizzled] then B same. 3 x 32KB = 96KB.
// Swizzle (both sides, rule 21): slot(r, chunk c) = c ^ ((r>>1)&3).

#define STAGE(BUF, TT) do {                                                              \
    int t_ = (TT);                                                                       \
    _Pragma("unroll")                                                                    \
    for (int s_ = 0; s_ < 2; ++s_) {                                                     \
        __builtin_amdgcn_global_load_lds(                                                \
            (const __attribute__((address_space(1))) void*)(gA + (size_t)(s_ * 128 + rowq) * 1024 + t_ * 32 + ch * 8), \
            (__attribute__((address_space(3))) void*)(&lds[(BUF) * 16384 + s_ * 4096 + tid * 8]), 16, 0, 0); \
        __builtin_amdgcn_global_load_lds(                                                \
            (const __attribute__((address_space(1))) void*)(gB + (size_t)(s_ * 128 + rowq) * 1024 + t_ * 32 + ch * 8), \
            (__attribute__((address_space(3))) void*)(&lds[(BUF) * 16384 + 8192 + s_ * 4096 + tid * 8]), 16, 0, 0); \
    }                                                                                    \
} while (0)

#define DS_MFMA(BCUR) do {                                                               \
    bf16x8 af[8], bv[4];                                                                 \
    const unsigned short* pA = &lds[(BCUR) * 16384 + (wmBase + fr) * 32 + sx];           \
    const unsigned short* pB = &lds[(BCUR) * 16384 + 8192 + (wnBase + fr) * 32 + sx];    \
    _Pragma("unroll")                                                                    \
    for (int m = 0; m < 8; ++m) af[m] = *reinterpret_cast<const bf16x8*>(pA + m * 512);  \
    _Pragma("unroll")                                                                    \
    for (int n = 0; n < 4; ++n) bv[n] = *reinterpret_cast<const bf16x8*>(pB + n * 512);  \
    asm volatile("s_waitcnt lgkmcnt(0)" ::: "memory");                                   \
    __builtin_amdgcn_s_barrier();                                                        \
    __builtin_amdgcn_s_setprio(1);                                                       \
    _Pragma("unroll")                                                                    \
    for (int m = 0; m < 8; ++m)                                                          \
        _Pragma("unroll")                                                                \
        for (int n = 0; n < 4; ++n)                                                      \
            acc[m][n] = __builtin_amdgcn_mfma_f32_16x16x32_bf16(af[m], bv[n], acc[m][n], 0, 0, 0); \
    __builtin_amdgcn_s_setprio(0);                                                       \
} while (0)

#define GEMM_ITER(BCUR, BSTG, TN) do {                                                   \
    STAGE(BSTG, TN);                                                                     \
    asm volatile("s_waitcnt vmcnt(8)" ::: "memory");                                     \
    __builtin_amdgcn_s_barrier();                                                        \
    DS_MFMA(BCUR);                                                                       \
} while (0)

__global__ __launch_bounds__(512, 2) void gemm_min_kernel(const unsigned short* __restrict__ emb,
                                                          const unsigned short* __restrict__ csb,
                                                          const float* __restrict__ x2,
                                                          const float* __restrict__ y2,
                                                          unsigned* __restrict__ d2u) {
    __shared__ unsigned short lds[49152]; // 3 x (A 8192 + B 8192) shorts = 96 KB

    int bid = blockIdx.x;
    // XCD-aware supertile walk: XCD owns 16 cs-tiles; 4x4 supertiles (4MB) fit L2.
    int xcd   = bid & 7;
    int local = bid >> 3;        // 0..511
    int st    = local >> 4;      // 0..31
    int idx   = local & 15;
    int si = idx >> 2, sj = idx & 3;
    int emb_tile = (st & 7) * 4 + si;            // 0..31
    int cs_tile  = xcd * 16 + (st >> 3) * 4 + sj; // 0..127
    int nb = emb_tile * 256;
    int mb = cs_tile * 256;

    int tid  = threadIdx.x;
    int lane = tid & 63;
    int wid  = tid >> 6;         // 0..7
    int wmBase = (wid >> 2) * 128;
    int wnBase = (wid & 3) * 64;

    // staging addressing
    int rowq = tid >> 2;                          // 0..127
    int ch   = (tid & 3) ^ ((tid >> 3) & 3);      // swizzled source chunk
    const unsigned short* gA = emb + (size_t)nb * 1024;
    const unsigned short* gB = csb + (size_t)mb * 1024;

    // fragment read addressing
    int fr = lane & 15;
    int kq = lane >> 4;
    int sx = (kq ^ ((fr >> 1) & 3)) * 8;          // swizzled slot (shorts)

    f32x4 acc[8][4];
    #pragma unroll
    for (int m = 0; m < 8; ++m)
        #pragma unroll
        for (int n = 0; n < 4; ++n) acc[m][n] = (f32x4){0.f, 0.f, 0.f, 0.f};

    // prologue: stage K0 -> buf0, K1 -> buf1
    STAGE(0, 0);
    STAGE(1, 1);

    // main loop: 30 iterations (u = 0..29), triple-unrolled for static buffer bases
    #pragma unroll 1
    for (int u = 0; u < 30; u += 3) {
        GEMM_ITER(0, 2, u + 2);
        GEMM_ITER(1, 0, u + 3);
        GEMM_ITER(2, 1, u + 4);
    }
    // tail: K30 in buf0 (wait K30: 4 outstanding after it), K31 in buf1
    asm volatile("s_waitcnt vmcnt(4)" ::: "memory");
    __builtin_amdgcn_s_barrier();
    DS_MFMA(0);
    asm volatile("s_waitcnt vmcnt(0)" ::: "memory");
    __builtin_amdgcn_s_barrier();
    DS_MFMA(1);

    // epilogue: d2 = x2[row] + y2[col] - 2*dot; min over 64 cols of this wave
    // C/D layout: col = lane&15, row = (lane>>4)*4 + reg  [m89]
    int cc = lane & 15;
    int rq = (lane >> 4) * 4;
    float y2v[4];
    #pragma unroll
    for (int n = 0; n < 4; ++n) y2v[n] = y2[mb + wnBase + n * 16 + cc];

    #pragma unroll
    for (int m = 0; m < 8; ++m) {
        #pragma unroll
        for (int j = 0; j < 4; ++j) {
            float v = y2v[0] - 2.0f * acc[m][0][j];
            #pragma unroll
            for (int n = 1; n < 4; ++n) v = fminf(v, y2v[n] - 2.0f * acc[m][n][j]);
            int grow = nb + wmBase + m * 16 + rq + j;
            float d2 = x2[grow] + v;
            d2 = fmaxf(d2, EPS_);
            #pragma unroll
            for (int off = 1; off < 16; off <<= 1) d2 = fminf(d2, __shfl_xor(d2, off));
            if (cc == 0) atomicMin(&d2u[grow], __float_as_uint(d2));
        }
    }
}

// ---------------- finalize ----------------
__global__ void sqrt_kernel(const unsigned* __restrict__ d2u, float* __restrict__ out) {
    int i = blockIdx.x * blockDim.x + threadIdx.x;
    if (i < N_TOT) out[i] = sqrtf(__uint_as_float(d2u[i]));
}

extern "C" void kernel_launch(void* const* d_in, const int* in_sizes, int n_in,
                              void* d_out, int out_size, void* d_ws, size_t ws_size,
                              hipStream_t stream) {
    const float* feat = (const float*)d_in[0];   // [8,1024,32,32] fp32
    const float* cs   = (const float*)d_in[1];   // [32768,1024] fp32
    float* out = (float*)d_out;                  // [8192] fp32

    char* ws = (char*)d_ws;
    unsigned short* emb = (unsigned short*)ws;                          // 16 MB
    unsigned short* csb = (unsigned short*)(ws + 16777216);             // 64 MB
    float* x2 = (float*)(ws + 16777216 + 67108864);
    float* y2 = x2 + N_TOT;
    unsigned* d2u = (unsigned*)(y2 + M_TOT);

    init_kernel<<<N_TOT / 256, 256, 0, stream>>>(d2u, x2);
    pool_kernel<<<8192, 256, 0, stream>>>(feat, emb, x2);
    cs_kernel<<<M_TOT, 256, 0, stream>>>(cs, csb, y2);
    gemm_min_kernel<<<4096, 512, 0, stream>>>(emb, csb, x2, y2, d2u);
    sqrt_kernel<<<N_TOT / 256, 256, 0, stream>>>(d2u, out);
}